// Round 4
// baseline (327.060 us; speedup 1.0000x reference)
//
#include <hip/hip_runtime.h>

// Problem constants (match reference)
#define N1 8192
#define N2 8192
#define FM 256
#define FD 256
#define FOUT 128

typedef float f4 __attribute__((ext_vector_type(4)));

// Workspace layout (floats):
//   [0,   256)  v_m = w_m @ a[:128]
//   [256, 512)  v_d = w_d @ a[128:]
//   [512, 512+8192)        s1
//   [512+8192, 512+16384)  s2

// --- Kernel 1: v_m[k] = sum_j w_m[k,j]*a[j];  v_d[k] = sum_j w_d[k,j]*a[128+j]
// 128 blocks x 256 threads (4 waves); one wave per output k (512 outputs).
__global__ void __launch_bounds__(256) compute_v(const float* __restrict__ w_m,
                                                 const float* __restrict__ w_d,
                                                 const float* __restrict__ a,
                                                 float* __restrict__ ws) {
    int wid = blockIdx.x * 4 + (threadIdx.x >> 6);   // 0..511
    int t   = threadIdx.x & 63;
    const float* w;
    const float* av;
    float* dst;
    int k;
    if (wid < 256) { w = w_m; av = a;       dst = ws;       k = wid; }
    else           { w = w_d; av = a + 128; dst = ws + 256; k = wid - 256; }
    float p = w[k * FOUT + t] * av[t] + w[k * FOUT + 64 + t] * av[64 + t];
    #pragma unroll
    for (int o = 32; o > 0; o >>= 1) p += __shfl_xor(p, o, 64);
    if (t == 0) dst[k] = p;
}

// --- Kernel 2: s1[i] = sum_k (am0*m+am1*m1+am2*m2)[i,k] * v_m[k]  (s2 likewise)
// 2048 blocks x 256 threads = 8192 waves; wave w does m-row w AND d-row w.
__global__ void __launch_bounds__(256) compute_s(const float* __restrict__ m0,
                                                 const float* __restrict__ m1,
                                                 const float* __restrict__ m2,
                                                 const float* __restrict__ d0,
                                                 const float* __restrict__ d1,
                                                 const float* __restrict__ d2,
                                                 const float* __restrict__ am,
                                                 const float* __restrict__ ad,
                                                 const float* __restrict__ v,   // v_m at 0, v_d at 256
                                                 float* __restrict__ s) {       // s1 at 0, s2 at 8192
    int w = blockIdx.x * 4 + (threadIdx.x >> 6);     // row 0..8191
    int t = threadIdx.x & 63;
    size_t base = (size_t)w * FM + t * 4;

    // m-side
    {
        float c0 = am[0], c1 = am[1], c2 = am[2];
        const f4 a0 = *(const f4*)(m0 + base);
        const f4 a1 = *(const f4*)(m1 + base);
        const f4 a2 = *(const f4*)(m2 + base);
        const f4 vq = *(const f4*)(v + t * 4);
        float p = (c0 * a0.x + c1 * a1.x + c2 * a2.x) * vq.x
                + (c0 * a0.y + c1 * a1.y + c2 * a2.y) * vq.y
                + (c0 * a0.z + c1 * a1.z + c2 * a2.z) * vq.z
                + (c0 * a0.w + c1 * a1.w + c2 * a2.w) * vq.w;
        #pragma unroll
        for (int o = 32; o > 0; o >>= 1) p += __shfl_xor(p, o, 64);
        if (t == 0) s[w] = p;
    }
    // d-side
    {
        float c0 = ad[0], c1 = ad[1], c2 = ad[2];
        const f4 a0 = *(const f4*)(d0 + base);
        const f4 a1 = *(const f4*)(d1 + base);
        const f4 a2 = *(const f4*)(d2 + base);
        const f4 vq = *(const f4*)(v + 256 + t * 4);
        float p = (c0 * a0.x + c1 * a1.x + c2 * a2.x) * vq.x
                + (c0 * a0.y + c1 * a1.y + c2 * a2.y) * vq.y
                + (c0 * a0.z + c1 * a1.z + c2 * a2.z) * vq.z
                + (c0 * a0.w + c1 * a1.w + c2 * a2.w) * vq.w;
        #pragma unroll
        for (int o = 32; o > 0; o >>= 1) p += __shfl_xor(p, o, 64);
        if (t == 0) s[N1 + w] = p;
    }
}

// mish(x) = x * tanh(softplus(x)).
// With t = e^x:  tanh(ln(1+t)) = (t^2+2t)/(t^2+2t+2).
// Clamp exp arg at 40: t^2 <= 5.5e34 stays finite; for x>40 ratio==1 to 1e-35.
__device__ __forceinline__ float mish_f(float x) {
    float t = __expf(fminf(x, 40.0f));
    float w = t * (t + 2.0f);
    float r = __builtin_amdgcn_rcpf(w + 2.0f);
    return x * (w * r);
}

// --- Kernel 3: e[i,j] = mish(s1[i] + s2[j]).  Write-bound: 256 MB f32.
// 2048 blocks x 256 threads, 32 float4 per thread, grid-stride 524288 float4.
// Stride mod row-width == 0  =>  each thread's j is loop-invariant (s2 in regs);
// only the block-uniform s1[i] changes per iteration (scalar load).
__global__ void __launch_bounds__(256) compute_e(const float* __restrict__ s,  // s1 at 0, s2 at 8192
                                                 float* __restrict__ out) {
    int tgl = blockIdx.x * 256 + threadIdx.x;        // 0..524287
    int j4  = tgl & 2047;                            // float4 col, invariant
    int i0  = tgl >> 11;                             // 0..255, block-uniform
    const f4 sv = *(const f4*)(s + N1 + j4 * 4);

    f4* outv = (f4*)out;
    #pragma unroll 4
    for (int it = 0; it < 32; ++it) {
        int i = i0 + it * 256;
        float x = s[i];                              // uniform -> scalar load
        f4 r;
        r.x = mish_f(x + sv.x);
        r.y = mish_f(x + sv.y);
        r.z = mish_f(x + sv.z);
        r.w = mish_f(x + sv.w);
        outv[(size_t)i * (N2 / 4) + j4] = r;
    }
}

extern "C" void kernel_launch(void* const* d_in, const int* in_sizes, int n_in,
                              void* d_out, int out_size, void* d_ws, size_t ws_size,
                              hipStream_t stream) {
    const float* m   = (const float*)d_in[0];
    const float* m1  = (const float*)d_in[1];
    const float* m2  = (const float*)d_in[2];
    const float* d0  = (const float*)d_in[3];
    const float* d1  = (const float*)d_in[4];
    const float* d2  = (const float*)d_in[5];
    // d_in[6] = adj (unused by forward)
    const float* w_m = (const float*)d_in[7];
    const float* w_d = (const float*)d_in[8];
    const float* a_m = (const float*)d_in[9];
    const float* a_d = (const float*)d_in[10];
    const float* a   = (const float*)d_in[11];

    float* ws = (float*)d_ws;
    float* v  = ws;          // v_m[256] then v_d[256]
    float* s  = ws + 512;    // s1[8192] then s2[8192]
    float* out = (float*)d_out;

    compute_v<<<128, 256, 0, stream>>>(w_m, w_d, a, ws);
    compute_s<<<2048, 256, 0, stream>>>(m, m1, m2, d0, d1, d2, a_m, a_d, v, s);
    compute_e<<<2048, 256, 0, stream>>>(s, out);
}

// Round 6
// 326.010 us; speedup vs baseline: 1.0032x; 1.0032x over previous
//
#include <hip/hip_runtime.h>

// Problem constants (match reference)
#define N1 8192
#define N2 8192
#define FM 256
#define FD 256
#define FOUT 128

typedef float f4 __attribute__((ext_vector_type(4)));

// Workspace layout (floats):
//   [0,   256)  v_m = w_m @ a[:128]
//   [256, 512)  v_d = w_d @ a[128:]
//   [512, 512+8192)        s1
//   [512+8192, 512+16384)  s2

// --- Kernel 1: v_m[k] = sum_j w_m[k,j]*a[j];  v_d[k] = sum_j w_d[k,j]*a[128+j]
// 128 blocks x 256 threads (4 waves); one wave per output k (512 outputs).
__global__ void __launch_bounds__(256) compute_v(const float* __restrict__ w_m,
                                                 const float* __restrict__ w_d,
                                                 const float* __restrict__ a,
                                                 float* __restrict__ ws) {
    int wid = blockIdx.x * 4 + (threadIdx.x >> 6);   // 0..511
    int t   = threadIdx.x & 63;
    const float* w;
    const float* av;
    float* dst;
    int k;
    if (wid < 256) { w = w_m; av = a;       dst = ws;       k = wid; }
    else           { w = w_d; av = a + 128; dst = ws + 256; k = wid - 256; }
    float p = w[k * FOUT + t] * av[t] + w[k * FOUT + 64 + t] * av[64 + t];
    #pragma unroll
    for (int o = 32; o > 0; o >>= 1) p += __shfl_xor(p, o, 64);
    if (t == 0) dst[k] = p;
}

// --- Kernel 2: s1[i] = sum_k (am0*m+am1*m1+am2*m2)[i,k] * v_m[k]  (s2 likewise)
// 2048 blocks x 256 threads = 8192 waves; wave w does m-row w AND d-row w.
// Streamed inputs (never reused) use nontemporal loads; row index forced to SGPR.
__global__ void __launch_bounds__(256) compute_s(const float* __restrict__ m0,
                                                 const float* __restrict__ m1,
                                                 const float* __restrict__ m2,
                                                 const float* __restrict__ d0,
                                                 const float* __restrict__ d1,
                                                 const float* __restrict__ d2,
                                                 const float* __restrict__ am,
                                                 const float* __restrict__ ad,
                                                 const float* __restrict__ v,   // v_m at 0, v_d at 256
                                                 float* __restrict__ s) {       // s1 at 0, s2 at 8192
    int w = __builtin_amdgcn_readfirstlane(blockIdx.x * 4 + (threadIdx.x >> 6)); // wave-uniform row
    int t = threadIdx.x & 63;
    size_t base = (size_t)w * FM + t * 4;

    // m-side
    {
        float c0 = am[0], c1 = am[1], c2 = am[2];
        const f4 a0 = __builtin_nontemporal_load((const f4*)(m0 + base));
        const f4 a1 = __builtin_nontemporal_load((const f4*)(m1 + base));
        const f4 a2 = __builtin_nontemporal_load((const f4*)(m2 + base));
        const f4 vq = *(const f4*)(v + t * 4);
        float p = (c0 * a0.x + c1 * a1.x + c2 * a2.x) * vq.x
                + (c0 * a0.y + c1 * a1.y + c2 * a2.y) * vq.y
                + (c0 * a0.z + c1 * a1.z + c2 * a2.z) * vq.z
                + (c0 * a0.w + c1 * a1.w + c2 * a2.w) * vq.w;
        #pragma unroll
        for (int o = 32; o > 0; o >>= 1) p += __shfl_xor(p, o, 64);
        if (t == 0) s[w] = p;
    }
    // d-side
    {
        float c0 = ad[0], c1 = ad[1], c2 = ad[2];
        const f4 a0 = __builtin_nontemporal_load((const f4*)(d0 + base));
        const f4 a1 = __builtin_nontemporal_load((const f4*)(d1 + base));
        const f4 a2 = __builtin_nontemporal_load((const f4*)(d2 + base));
        const f4 vq = *(const f4*)(v + 256 + t * 4);
        float p = (c0 * a0.x + c1 * a1.x + c2 * a2.x) * vq.x
                + (c0 * a0.y + c1 * a1.y + c2 * a2.y) * vq.y
                + (c0 * a0.z + c1 * a1.z + c2 * a2.z) * vq.z
                + (c0 * a0.w + c1 * a1.w + c2 * a2.w) * vq.w;
        #pragma unroll
        for (int o = 32; o > 0; o >>= 1) p += __shfl_xor(p, o, 64);
        if (t == 0) s[N1 + w] = p;
    }
}

// mish(x) = x * tanh(softplus(x)).
// With t = e^x:  tanh(ln(1+t)) = (t^2+2t)/(t^2+2t+2).
// Clamp exp arg at 40: t^2 <= 5.5e34 stays finite; for x>40 ratio==1 to 1e-35.
__device__ __forceinline__ float mish_f(float x) {
    float t = __expf(fminf(x, 40.0f));
    float w = t * (t + 2.0f);
    float r = __builtin_amdgcn_rcpf(w + 2.0f);
    return x * (w * r);
}

// --- Kernel 3: e[i,j] = mish(s1[i] + s2[j]).  Write-bound: 256 MB f32.
// 2048 blocks x 256 threads, 32 float4/thread.  j is loop-invariant (s2 in regs);
// the 32 block-uniform s1 values are batch-preloaded into SGPRs (readfirstlane
// guarantees scalar addressing), so the store loop has no dependent vector load.
// Output is write-once-never-read: nontemporal stores keep it out of L2.
__global__ void __launch_bounds__(256) compute_e(const float* __restrict__ s,  // s1 at 0, s2 at 8192
                                                 float* __restrict__ out) {
    int tgl = blockIdx.x * 256 + threadIdx.x;        // 0..524287
    int j4  = tgl & 2047;                            // float4 col, invariant per thread
    // (b*256 + t) >> 11 never crosses a 2048 boundary within a block -> uniform.
    int i0  = __builtin_amdgcn_readfirstlane(tgl >> 11);   // 0..255, SGPR

    const f4 sv = *(const f4*)(s + N1 + j4 * 4);

    float xs[32];
    #pragma unroll
    for (int it = 0; it < 32; ++it)
        xs[it] = s[i0 + it * 256];                   // uniform addr -> s_load, pipelined

    f4* outv = (f4*)out;
    #pragma unroll 8
    for (int it = 0; it < 32; ++it) {
        int i = i0 + it * 256;
        float x = xs[it];
        f4 r;
        r.x = mish_f(x + sv.x);
        r.y = mish_f(x + sv.y);
        r.z = mish_f(x + sv.z);
        r.w = mish_f(x + sv.w);
        __builtin_nontemporal_store(r, &outv[(size_t)i * (N2 / 4) + j4]);
    }
}

extern "C" void kernel_launch(void* const* d_in, const int* in_sizes, int n_in,
                              void* d_out, int out_size, void* d_ws, size_t ws_size,
                              hipStream_t stream) {
    const float* m   = (const float*)d_in[0];
    const float* m1  = (const float*)d_in[1];
    const float* m2  = (const float*)d_in[2];
    const float* d0  = (const float*)d_in[3];
    const float* d1  = (const float*)d_in[4];
    const float* d2  = (const float*)d_in[5];
    // d_in[6] = adj (unused by forward)
    const float* w_m = (const float*)d_in[7];
    const float* w_d = (const float*)d_in[8];
    const float* a_m = (const float*)d_in[9];
    const float* a_d = (const float*)d_in[10];
    const float* a   = (const float*)d_in[11];

    float* ws = (float*)d_ws;
    float* v  = ws;          // v_m[256] then v_d[256]
    float* s  = ws + 512;    // s1[8192] then s2[8192]
    float* out = (float*)d_out;

    compute_v<<<128, 256, 0, stream>>>(w_m, w_d, a, ws);
    compute_s<<<2048, 256, 0, stream>>>(m, m1, m2, d0, d1, d2, a_m, a_d, v, s);
    compute_e<<<2048, 256, 0, stream>>>(s, out);
}

// Round 7
// 317.276 us; speedup vs baseline: 1.0308x; 1.0275x over previous
//
#include <hip/hip_runtime.h>

// Problem constants (match reference)
#define N1 8192
#define N2 8192
#define FM 256
#define FD 256
#define FOUT 128

typedef float f4 __attribute__((ext_vector_type(4)));

// Workspace layout (floats):
//   [0,   256)  v_m = w_m @ a[:128]
//   [256, 512)  v_d = w_d @ a[128:]
//   [512, 512+8192)        s1
//   [512+8192, 512+16384)  s2

// --- Kernel 1: v_m[k] = sum_j w_m[k,j]*a[j];  v_d[k] = sum_j w_d[k,j]*a[128+j]
// 128 blocks x 256 threads (4 waves); one wave per output k (512 outputs).
__global__ void __launch_bounds__(256) compute_v(const float* __restrict__ w_m,
                                                 const float* __restrict__ w_d,
                                                 const float* __restrict__ a,
                                                 float* __restrict__ ws) {
    int wid = blockIdx.x * 4 + (threadIdx.x >> 6);   // 0..511
    int t   = threadIdx.x & 63;
    const float* w;
    const float* av;
    float* dst;
    int k;
    if (wid < 256) { w = w_m; av = a;       dst = ws;       k = wid; }
    else           { w = w_d; av = a + 128; dst = ws + 256; k = wid - 256; }
    float p = w[k * FOUT + t] * av[t] + w[k * FOUT + 64 + t] * av[64 + t];
    #pragma unroll
    for (int o = 32; o > 0; o >>= 1) p += __shfl_xor(p, o, 64);
    if (t == 0) dst[k] = p;
}

// --- Kernel 2: s1[i] = sum_k (am0*m+am1*m1+am2*m2)[i,k] * v_m[k]  (s2 likewise)
// 2048 blocks x 256 threads = 8192 waves; wave w does m-row w AND d-row w.
__global__ void __launch_bounds__(256) compute_s(const float* __restrict__ m0,
                                                 const float* __restrict__ m1,
                                                 const float* __restrict__ m2,
                                                 const float* __restrict__ d0,
                                                 const float* __restrict__ d1,
                                                 const float* __restrict__ d2,
                                                 const float* __restrict__ am,
                                                 const float* __restrict__ ad,
                                                 const float* __restrict__ v,   // v_m at 0, v_d at 256
                                                 float* __restrict__ s) {       // s1 at 0, s2 at 8192
    int w = __builtin_amdgcn_readfirstlane(blockIdx.x * 4 + (threadIdx.x >> 6)); // wave-uniform row
    int t = threadIdx.x & 63;
    size_t base = (size_t)w * FM + t * 4;

    // m-side
    {
        float c0 = am[0], c1 = am[1], c2 = am[2];
        const f4 a0 = __builtin_nontemporal_load((const f4*)(m0 + base));
        const f4 a1 = __builtin_nontemporal_load((const f4*)(m1 + base));
        const f4 a2 = __builtin_nontemporal_load((const f4*)(m2 + base));
        const f4 vq = *(const f4*)(v + t * 4);
        float p = (c0 * a0.x + c1 * a1.x + c2 * a2.x) * vq.x
                + (c0 * a0.y + c1 * a1.y + c2 * a2.y) * vq.y
                + (c0 * a0.z + c1 * a1.z + c2 * a2.z) * vq.z
                + (c0 * a0.w + c1 * a1.w + c2 * a2.w) * vq.w;
        #pragma unroll
        for (int o = 32; o > 0; o >>= 1) p += __shfl_xor(p, o, 64);
        if (t == 0) s[w] = p;
    }
    // d-side
    {
        float c0 = ad[0], c1 = ad[1], c2 = ad[2];
        const f4 a0 = __builtin_nontemporal_load((const f4*)(d0 + base));
        const f4 a1 = __builtin_nontemporal_load((const f4*)(d1 + base));
        const f4 a2 = __builtin_nontemporal_load((const f4*)(d2 + base));
        const f4 vq = *(const f4*)(v + 256 + t * 4);
        float p = (c0 * a0.x + c1 * a1.x + c2 * a2.x) * vq.x
                + (c0 * a0.y + c1 * a1.y + c2 * a2.y) * vq.y
                + (c0 * a0.z + c1 * a1.z + c2 * a2.z) * vq.z
                + (c0 * a0.w + c1 * a1.w + c2 * a2.w) * vq.w;
        #pragma unroll
        for (int o = 32; o > 0; o >>= 1) p += __shfl_xor(p, o, 64);
        if (t == 0) s[N1 + w] = p;
    }
}

// mish(x) = x * tanh(softplus(x)).
// With t = e^x:  tanh(ln(1+t)) = (t^2+2t)/(t^2+2t+2).
// Clamp exp arg at 40: t^2 <= 5.5e34 stays finite; for x>40 ratio==1 to 1e-35.
__device__ __forceinline__ float mish_f(float x) {
    float t = __expf(fminf(x, 40.0f));
    float w = t * (t + 2.0f);
    float r = __builtin_amdgcn_rcpf(w + 2.0f);
    return x * (w * r);
}

// --- Kernel 3: e[i,j] = mish(s1[i] + s2[j]).  Write-bound: 256 MB f32.
// FILL-LIKE WRITE PATTERN: block b owns rows [4b, 4b+4) = one contiguous
// 128 KB span.  Thread t walks it linearly: iter it stores float4 number
// (it*256 + t) of the span -> each wave writes 4 KB contiguous, the block
// streams sequentially, exactly like the 6.4 TB/s fill kernel.
// Reuse: 4 s1 scalars in SGPRs; the 8 distinct s2 float4s per thread
// (j4 = (it&7)*256 + t) preloaded in VGPRs; fully unrolled -> static indices.
__global__ void __launch_bounds__(256) compute_e(const float* __restrict__ s,  // s1 at 0, s2 at 8192
                                                 float* __restrict__ out) {
    int b = blockIdx.x;                  // 0..2047, uniform
    int t = threadIdx.x;                 // 0..255
    int r0 = __builtin_amdgcn_readfirstlane(b * 4);

    // 4 block-uniform row scalars -> SGPRs (scalar loads)
    float x0 = s[r0 + 0];
    float x1 = s[r0 + 1];
    float x2 = s[r0 + 2];
    float x3 = s[r0 + 3];

    // 8 reused s2 float4s per thread (coalesced: consecutive t -> consecutive addr)
    f4 sv[8];
    #pragma unroll
    for (int k = 0; k < 8; ++k)
        sv[k] = *(const f4*)(s + N1 + (k * 256 + t) * 4);

    f4* outv = (f4*)out + (size_t)b * 8192 + t;   // block's span, thread phase t
    #pragma unroll
    for (int it = 0; it < 32; ++it) {
        const int row = it >> 3;                  // 0..3 (compile-time)
        const float x = (row == 0) ? x0 : (row == 1) ? x1 : (row == 2) ? x2 : x3;
        const f4 v = sv[it & 7];                  // compile-time index
        f4 r;
        r.x = mish_f(x + v.x);
        r.y = mish_f(x + v.y);
        r.z = mish_f(x + v.z);
        r.w = mish_f(x + v.w);
        __builtin_nontemporal_store(r, outv + it * 256);
    }
}

extern "C" void kernel_launch(void* const* d_in, const int* in_sizes, int n_in,
                              void* d_out, int out_size, void* d_ws, size_t ws_size,
                              hipStream_t stream) {
    const float* m   = (const float*)d_in[0];
    const float* m1  = (const float*)d_in[1];
    const float* m2  = (const float*)d_in[2];
    const float* d0  = (const float*)d_in[3];
    const float* d1  = (const float*)d_in[4];
    const float* d2  = (const float*)d_in[5];
    // d_in[6] = adj (unused by forward)
    const float* w_m = (const float*)d_in[7];
    const float* w_d = (const float*)d_in[8];
    const float* a_m = (const float*)d_in[9];
    const float* a_d = (const float*)d_in[10];
    const float* a   = (const float*)d_in[11];

    float* ws = (float*)d_ws;
    float* v  = ws;          // v_m[256] then v_d[256]
    float* s  = ws + 512;    // s1[8192] then s2[8192]
    float* out = (float*)d_out;

    compute_v<<<128, 256, 0, stream>>>(w_m, w_d, a, ws);
    compute_s<<<2048, 256, 0, stream>>>(m, m1, m2, d0, d1, d2, a_m, a_d, v, s);
    compute_e<<<2048, 256, 0, stream>>>(s, out);
}